// Round 12
// baseline (285.548 us; speedup 1.0000x reference)
//
#include <hip/hip_runtime.h>
#include <cstdint>
#include <cstddef>

#define NEG_SLOPE 0.01f
#define BN_EPS 1e-5f
#define BSHIFT 6
#define BMASK 63
#define NBLK 128   // scatter chunks

using short8 = __attribute__((ext_vector_type(8))) short;
using f32x4 = __attribute__((ext_vector_type(4))) float;

__device__ inline unsigned short f2bf(float f) {   // RNE f32 -> bf16
    unsigned int u = __float_as_uint(f);
    u += 0x7FFFu + ((u >> 16) & 1u);
    return (unsigned short)(u >> 16);
}

// ---------------- pre: chunk histograms (blocks < NBLK) + W1/W2 transpose (rest) ----------------

__global__ __launch_bounds__(1024) void pre_kernel(const int* __restrict__ dst,
                                                   int* __restrict__ hist,
                                                   int E, int nb, int chunk,
                                                   const float* __restrict__ W1,
                                                   unsigned short* __restrict__ wt1,
                                                   const float* __restrict__ W2,
                                                   unsigned short* __restrict__ wt2) {
    const int b = blockIdx.x;
    if (b < NBLK) {
        __shared__ int lh[2048];
        for (int i = threadIdx.x; i < nb; i += 1024) lh[i] = 0;
        __syncthreads();
        const int e0 = b * chunk;
        const int e1 = min(E, e0 + chunk);
        for (int e = e0 + threadIdx.x; e < e1; e += 1024)
            atomicAdd(&lh[dst[e] >> BSHIFT], 1);
        __syncthreads();
        for (int k = threadIdx.x; k < nb; k += 1024)
            hist[k * NBLK + b] = lh[k];
    } else {
        int idx = (b - NBLK) * 1024 + threadIdx.x;
        if (idx < 128 * 128) {
            int k = idx >> 7, n = idx & 127;
            wt1[n * 128 + k] = f2bf(W1[idx]);
        } else if (idx < 128 * 128 + 128 * 64) {
            int j = idx - 128 * 128;
            int k = j >> 6, n = j & 63;
            wt2[n * 128 + k] = f2bf(W2[j]);
        }
    }
}

__global__ __launch_bounds__(1024) void scan_block_kernel(const int* __restrict__ in,
                                                          int* __restrict__ out,
                                                          int* __restrict__ partials, int n) {
    __shared__ int sm[1024];
    int tid = threadIdx.x;
    int i = blockIdx.x * 1024 + tid;
    int v = (i < n) ? in[i] : 0;
    int x = v;
    sm[tid] = x;
    __syncthreads();
    for (int off = 1; off < 1024; off <<= 1) {
        int y = (tid >= off) ? sm[tid - off] : 0;
        __syncthreads();
        x += y;
        sm[tid] = x;
        __syncthreads();
    }
    if (i < n) out[i] = x - v;           // exclusive
    if (tid == 1023) partials[blockIdx.x] = x;
}

// scatter: LDS cursors = scan + inline block-offset prefix (built from partials in LDS)
__global__ __launch_bounds__(1024) void chunkscatter_kernel(const int* __restrict__ src,
                                                            const int* __restrict__ dst,
                                                            const int* __restrict__ S,
                                                            const int* __restrict__ partials,
                                                            unsigned int* __restrict__ packed,
                                                            int E, int nb, int chunk, int MB) {
    __shared__ int cur[2048];
    __shared__ int pof[256];
    const int b = blockIdx.x;
    if (threadIdx.x == 0) {
        int acc = 0;
        for (int i = 0; i < MB; ++i) { pof[i] = acc; acc += partials[i]; }
    }
    __syncthreads();
    for (int k = threadIdx.x; k < nb; k += 1024) {
        const int i = k * NBLK + b;
        cur[k] = S[i] + pof[i >> 10];
    }
    __syncthreads();
    const int e0 = b * chunk;
    const int e1 = min(E, e0 + chunk);
    for (int e = e0 + threadIdx.x; e < e1; e += 1024) {
        int d = dst[e];
        int slot = atomicAdd(&cur[d >> BSHIFT], 1);
        packed[slot] = ((unsigned int)src[e] << BSHIFT) | (unsigned int)(d & BMASK);
    }
}

// per-bucket: counting sort by (ldst, src>>13) -> rowptr, dinv, src-binned csr lists.
__global__ __launch_bounds__(256) void bucket_build_kernel(const unsigned int* __restrict__ packed,
                                                           const int* __restrict__ S,
                                                           const int* __restrict__ partials,
                                                           int* __restrict__ rowptr,
                                                           float* __restrict__ dinv,
                                                           int* __restrict__ csr,
                                                           int N, int nb, int E, int MB) {
    const int b = blockIdx.x;
    const int t = threadIdx.x;
    __shared__ int pof[256];
    __shared__ int eb[2];
    if (t == 0) {
        int acc = 0;
        for (int i = 0; i < MB; ++i) { pof[i] = acc; acc += partials[i]; }
        const int i0 = b * NBLK;
        eb[0] = S[i0] + pof[i0 >> 10];
        if (b == nb - 1) eb[1] = E;
        else {
            const int i1 = (b + 1) * NBLK;
            eb[1] = S[i1] + pof[i1 >> 10];
        }
    }
    __syncthreads();
    const int e0 = eb[0], e1 = eb[1];
    const int node0 = b << BSHIFT;
    __shared__ int h2[1024];    // [ldst][16] sub-bin hist -> exclusive scan -> cursors
    __shared__ int tsum[256];
    for (int i = t; i < 1024; i += 256) h2[i] = 0;
    __syncthreads();
    for (int e = e0 + t; e < e1; e += 256) {
        const unsigned int p = packed[e];
        const int ldst = p & BMASK;
        int s4 = (int)(p >> BSHIFT) >> 13;      // 0..12 for N=100000
        if (s4 > 15) s4 = 15;
        atomicAdd(&h2[(ldst << 4) | s4], 1);
    }
    __syncthreads();
    // exclusive scan of 1024 entries (4 per thread)
    const int v0 = h2[4 * t], v1 = h2[4 * t + 1], v2 = h2[4 * t + 2], v3 = h2[4 * t + 3];
    const int tot = v0 + v1 + v2 + v3;
    int x = tot;
    tsum[t] = x;
    __syncthreads();
    for (int o = 1; o < 256; o <<= 1) {
        int y = (t >= o) ? tsum[t - o] : 0;
        __syncthreads();
        x += y;
        tsum[t] = x;
        __syncthreads();
    }
    const int base = e0 + x - tot;
    h2[4 * t] = base;
    h2[4 * t + 1] = base + v0;
    h2[4 * t + 2] = base + v0 + v1;
    h2[4 * t + 3] = base + v0 + v1 + v2;
    __syncthreads();
    if (t < 64) {
        const int gs = h2[t << 4];
        const int ge = (t == 63) ? e1 : h2[(t + 1) << 4];
        const int node = node0 + t;
        if (node < N) {
            rowptr[node] = gs;
            dinv[node] = rsqrtf((float)(ge - gs + 1));   // +1 self-loop
        }
    }
    if (b == nb - 1 && t == 0) rowptr[N] = E;
    __syncthreads();
    for (int e = e0 + t; e < e1; e += 256) {
        const unsigned int p = packed[e];
        const int ldst = p & BMASK;
        const int src = (int)(p >> BSHIFT);
        int s4 = src >> 13;
        if (s4 > 15) s4 = 15;
        const int slot = atomicAdd(&h2[(ldst << 4) | s4], 1);
        csr[slot] = src;
    }
}

// ---------------- MFMA GEMM: H'[row] = bf16( dinv[row] * (bn(X)[row] @ W) ) ----------------

template <int MF, bool BN, bool XBF>
__global__ __launch_bounds__(256) void mgemm_kernel(const void* __restrict__ Xv,
                                                    const unsigned short* __restrict__ Wt,
                                                    const float* __restrict__ bnS,
                                                    const float* __restrict__ bnT,
                                                    const float* __restrict__ dinv,
                                                    unsigned short* __restrict__ H, int n) {
    constexpr int K = 128;
    constexpr int CTW = (MF / 16) / 4;           // col-tiles per wave (2 or 1)
    __shared__ unsigned short Xl[64 * K];        // 16 KB, reused as output tile
    __shared__ unsigned short Wl[MF * K];        // 32/16 KB
    __shared__ float dl[64];

    const int t = threadIdx.x;
    const int wave = t >> 6;
    const int lane = t & 63;
    const int row0 = blockIdx.x * 64;

    if (XBF) {
        const unsigned short* X = (const unsigned short*)Xv;
        for (int idx = t; idx < 64 * K / 8; idx += 256) {
            int r = idx >> 4, c8 = idx & 15;
            int row = row0 + r; if (row >= n) row = n - 1;
            uint4 v = ((const uint4*)(X + (size_t)row * K))[c8];
            float xv[8];
            xv[0] = __uint_as_float(v.x << 16); xv[1] = __uint_as_float(v.x & 0xFFFF0000u);
            xv[2] = __uint_as_float(v.y << 16); xv[3] = __uint_as_float(v.y & 0xFFFF0000u);
            xv[4] = __uint_as_float(v.z << 16); xv[5] = __uint_as_float(v.z & 0xFFFF0000u);
            xv[6] = __uint_as_float(v.w << 16); xv[7] = __uint_as_float(v.w & 0xFFFF0000u);
            if (BN) {
                const float4 s0 = ((const float4*)bnS)[c8 * 2];
                const float4 s1 = ((const float4*)bnS)[c8 * 2 + 1];
                const float4 t0 = ((const float4*)bnT)[c8 * 2];
                const float4 t1 = ((const float4*)bnT)[c8 * 2 + 1];
                xv[0] = xv[0] * s0.x + t0.x; xv[1] = xv[1] * s0.y + t0.y;
                xv[2] = xv[2] * s0.z + t0.z; xv[3] = xv[3] * s0.w + t0.w;
                xv[4] = xv[4] * s1.x + t1.x; xv[5] = xv[5] * s1.y + t1.y;
                xv[6] = xv[6] * s1.z + t1.z; xv[7] = xv[7] * s1.w + t1.w;
            }
            uint4 o;
            o.x = (unsigned)f2bf(xv[0]) | ((unsigned)f2bf(xv[1]) << 16);
            o.y = (unsigned)f2bf(xv[2]) | ((unsigned)f2bf(xv[3]) << 16);
            o.z = (unsigned)f2bf(xv[4]) | ((unsigned)f2bf(xv[5]) << 16);
            o.w = (unsigned)f2bf(xv[6]) | ((unsigned)f2bf(xv[7]) << 16);
            *(uint4*)((char*)Xl + r * 256 + ((c8 * 16) ^ ((r & 7) << 4))) = o;
        }
    } else {
        const float* X = (const float*)Xv;
        for (int idx = t; idx < 64 * K / 4; idx += 256) {
            int r = idx >> 5, c4 = idx & 31;
            int row = row0 + r; if (row >= n) row = n - 1;
            float4 v = ((const float4*)(X + (size_t)row * K))[c4];
            if (BN) {
                float4 sv = ((const float4*)bnS)[c4];
                float4 tv = ((const float4*)bnT)[c4];
                v.x = v.x * sv.x + tv.x; v.y = v.y * sv.y + tv.y;
                v.z = v.z * sv.z + tv.z; v.w = v.w * sv.w + tv.w;
            }
            ushort4 o; o.x = f2bf(v.x); o.y = f2bf(v.y); o.z = f2bf(v.z); o.w = f2bf(v.w);
            *(ushort4*)((char*)Xl + r * 256 + ((c4 * 8) ^ ((r & 7) << 4))) = o;
        }
    }
    for (int idx = t; idx < MF * K / 4; idx += 256) {
        int nr = idx >> 5, k4 = idx & 31;
        ushort4 o = ((const ushort4*)(Wt + (size_t)nr * K))[k4];
        *(ushort4*)((char*)Wl + nr * 256 + ((k4 * 8) ^ ((nr & 7) << 4))) = o;
    }
    if (t < 64) { int row = row0 + t; dl[t] = dinv[row < n ? row : n - 1]; }
    __syncthreads();

    f32x4 acc[CTW][4];
#pragma unroll
    for (int c = 0; c < CTW; ++c)
#pragma unroll
        for (int rt = 0; rt < 4; ++rt)
            acc[c][rt] = (f32x4){0.f, 0.f, 0.f, 0.f};

    const int kg = lane >> 4;       // k-group 0..3
    const int lr = lane & 15;       // row (A) / col (B)

#pragma unroll
    for (int kk = 0; kk < 4; ++kk) {
        const int kb = (kk * 32 + kg * 8) * 2;   // byte offset of the 8 bf16 k-slice
        short8 a[4];
#pragma unroll
        for (int rt = 0; rt < 4; ++rt) {
            int r = rt * 16 + lr;
            a[rt] = *(const short8*)((const char*)Xl + r * 256 + (kb ^ ((r & 7) << 4)));
        }
#pragma unroll
        for (int c = 0; c < CTW; ++c) {
            int nr = (wave * CTW + c) * 16 + lr;
            short8 b = *(const short8*)((const char*)Wl + nr * 256 + (kb ^ ((nr & 7) << 4)));
#pragma unroll
            for (int rt = 0; rt < 4; ++rt)
                acc[c][rt] = __builtin_amdgcn_mfma_f32_16x16x32_bf16(a[rt], b, acc[c][rt], 0, 0, 0);
        }
    }
    __syncthreads();   // done reading Xl; reuse as output tile [64][MF]

    unsigned short* Ol = (unsigned short*)Xl;
#pragma unroll
    for (int c = 0; c < CTW; ++c) {
        int col = (wave * CTW + c) * 16 + lr;
#pragma unroll
        for (int rt = 0; rt < 4; ++rt) {
#pragma unroll
            for (int j = 0; j < 4; ++j) {
                int r = rt * 16 + kg * 4 + j;
                Ol[r * MF + col] = f2bf(acc[c][rt][j] * dl[r]);
            }
        }
    }
    __syncthreads();
    for (int idx = t; idx < 64 * MF / 4; idx += 256) {
        int r = idx / (MF / 4), c4 = idx % (MF / 4);
        int row = row0 + r;
        if (row < n)
            ((ushort4*)(H + (size_t)row * MF))[c4] = ((const ushort4*)Ol)[idx];
    }
}

// ---------------- layer-3 GEMM: bf16 X [n][64] -> bf16 h3' [n][8] ----------------

__global__ __launch_bounds__(256) void gemm3_kernel(const unsigned short* __restrict__ X,
                                                    const float* __restrict__ W,   // [64][8]
                                                    const float* __restrict__ bnS,
                                                    const float* __restrict__ bnT,
                                                    const float* __restrict__ dinv,
                                                    unsigned short* __restrict__ H, int n) {
    __shared__ float Wl[512];
    __shared__ float sl[64], tl[64];
    const int t = threadIdx.x;
    for (int i = t; i < 512; i += 256) Wl[i] = W[i];
    if (t < 64) { sl[t] = bnS[t]; tl[t] = bnT[t]; }
    __syncthreads();
    const int node = blockIdx.x * 256 + t;
    if (node >= n) return;
    float acc[8];
#pragma unroll
    for (int m = 0; m < 8; ++m) acc[m] = 0.f;
    const uint4* xp = (const uint4*)(X + (size_t)node * 64);
#pragma unroll
    for (int c8 = 0; c8 < 8; ++c8) {
        const uint4 v = xp[c8];
        float xv[8];
        xv[0] = __uint_as_float(v.x << 16); xv[1] = __uint_as_float(v.x & 0xFFFF0000u);
        xv[2] = __uint_as_float(v.y << 16); xv[3] = __uint_as_float(v.y & 0xFFFF0000u);
        xv[4] = __uint_as_float(v.z << 16); xv[5] = __uint_as_float(v.z & 0xFFFF0000u);
        xv[6] = __uint_as_float(v.w << 16); xv[7] = __uint_as_float(v.w & 0xFFFF0000u);
#pragma unroll
        for (int j = 0; j < 8; ++j) {
            const int k = c8 * 8 + j;
            const float x = xv[j] * sl[k] + tl[k];
#pragma unroll
            for (int m = 0; m < 8; ++m) acc[m] += x * Wl[k * 8 + m];
        }
    }
    const float di = dinv[node];
    uint4 o;
    o.x = (unsigned)f2bf(acc[0] * di) | ((unsigned)f2bf(acc[1] * di) << 16);
    o.y = (unsigned)f2bf(acc[2] * di) | ((unsigned)f2bf(acc[3] * di) << 16);
    o.z = (unsigned)f2bf(acc[4] * di) | ((unsigned)f2bf(acc[5] * di) << 16);
    o.w = (unsigned)f2bf(acc[6] * di) | ((unsigned)f2bf(acc[7] * di) << 16);
    *(uint4*)(H + (size_t)node * 8) = o;
}

// ---------------- aggregation: y = leaky( di*(sum_row h'[s] + h'[self]) + b ) ----------------
// Exact grid, x4 unroll, VGPR 28 — measured-optimal concurrency shape (r7/r9: 60.8 us).
// n0 = start node of this launch's range (diagnostic node-range splitting, work-identical).

template <int F, int GROUP, bool BF16OUT>
__global__ __launch_bounds__(256) void agg_kernel(const unsigned short* __restrict__ h,
                                                  const int* __restrict__ rowptr,
                                                  const int* __restrict__ csr,
                                                  const float* __restrict__ dinv,
                                                  const float* __restrict__ bias,
                                                  void* __restrict__ yout, int n0, int n) {
    constexpr int NPB = 256 / GROUP;
    const int g = threadIdx.x % GROUP;
    const int node = n0 + blockIdx.x * NPB + threadIdx.x / GROUP;
    if (node >= n) return;
    const int f0 = g * 8;
    const unsigned short* hp = h + f0;
    float a0 = 0.f, a1 = 0.f, a2 = 0.f, a3 = 0.f, a4 = 0.f, a5 = 0.f, a6 = 0.f, a7 = 0.f;
#define ACC8(v)                                    \
    a0 += __uint_as_float((v).x << 16);            \
    a1 += __uint_as_float((v).x & 0xFFFF0000u);    \
    a2 += __uint_as_float((v).y << 16);            \
    a3 += __uint_as_float((v).y & 0xFFFF0000u);    \
    a4 += __uint_as_float((v).z << 16);            \
    a5 += __uint_as_float((v).z & 0xFFFF0000u);    \
    a6 += __uint_as_float((v).w << 16);            \
    a7 += __uint_as_float((v).w & 0xFFFF0000u);
    int e = rowptr[node];
    const int r1 = rowptr[node + 1];
    for (; e + 4 <= r1; e += 4) {
        const int s0 = csr[e], s1 = csr[e + 1], s2 = csr[e + 2], s3 = csr[e + 3];
        const uint4 v0 = *(const uint4*)(hp + (size_t)s0 * F);
        const uint4 v1 = *(const uint4*)(hp + (size_t)s1 * F);
        const uint4 v2 = *(const uint4*)(hp + (size_t)s2 * F);
        const uint4 v3 = *(const uint4*)(hp + (size_t)s3 * F);
        ACC8(v0); ACC8(v1); ACC8(v2); ACC8(v3);
    }
    for (; e < r1; ++e) {
        const int s = csr[e];
        const uint4 v = *(const uint4*)(hp + (size_t)s * F);
        ACC8(v);
    }
    {   // self term (h' already contains dinv[self] factor)
        const uint4 v = *(const uint4*)(hp + (size_t)node * F);
        ACC8(v);
    }
#undef ACC8
    const float di = dinv[node];
    const float4 bA = *(const float4*)(bias + f0);
    const float4 bB = *(const float4*)(bias + f0 + 4);
    float r[8];
    r[0] = di * a0 + bA.x; r[1] = di * a1 + bA.y;
    r[2] = di * a2 + bA.z; r[3] = di * a3 + bA.w;
    r[4] = di * a4 + bB.x; r[5] = di * a5 + bB.y;
    r[6] = di * a6 + bB.z; r[7] = di * a7 + bB.w;
#pragma unroll
    for (int k = 0; k < 8; ++k) r[k] = r[k] > 0.f ? r[k] : NEG_SLOPE * r[k];
    if (BF16OUT) {
        uint4 o;
        o.x = (unsigned)f2bf(r[0]) | ((unsigned)f2bf(r[1]) << 16);
        o.y = (unsigned)f2bf(r[2]) | ((unsigned)f2bf(r[3]) << 16);
        o.z = (unsigned)f2bf(r[4]) | ((unsigned)f2bf(r[5]) << 16);
        o.w = (unsigned)f2bf(r[6]) | ((unsigned)f2bf(r[7]) << 16);
        *(uint4*)((unsigned short*)yout + (size_t)node * F + f0) = o;
    } else {
        float4 o0, o1;
        o0.x = r[0]; o0.y = r[1]; o0.z = r[2]; o0.w = r[3];
        o1.x = r[4]; o1.y = r[5]; o1.z = r[6]; o1.w = r[7];
        float* yp = (float*)yout + (size_t)node * F + f0;
        *(float4*)(yp) = o0;
        *(float4*)(yp + 4) = o1;
    }
}

// ---------------- BN statistics over bf16 y: per-block partials ----------------

template <int F>
__global__ __launch_bounds__(256) void bstats_kernel(const unsigned short* __restrict__ y,
                                                     float* __restrict__ sumP,
                                                     float* __restrict__ ssqP,
                                                     int n, int nblocks) {
    constexpr int GROUP = F / 8;
    constexpr int NPB = 256 / GROUP;
    const int g = threadIdx.x % GROUP;
    const int slot = threadIdx.x / GROUP;
    const int f0 = g * 8;
    float ss[8], qq[8];
#pragma unroll
    for (int k = 0; k < 8; ++k) { ss[k] = 0.f; qq[k] = 0.f; }
    for (int base = blockIdx.x * NPB; base < n; base += nblocks * NPB) {
        const int node = base + slot;
        if (node < n) {
            const uint4 v = *(const uint4*)(y + (size_t)node * F + f0);
            float xv[8];
            xv[0] = __uint_as_float(v.x << 16); xv[1] = __uint_as_float(v.x & 0xFFFF0000u);
            xv[2] = __uint_as_float(v.y << 16); xv[3] = __uint_as_float(v.y & 0xFFFF0000u);
            xv[4] = __uint_as_float(v.z << 16); xv[5] = __uint_as_float(v.z & 0xFFFF0000u);
            xv[6] = __uint_as_float(v.w << 16); xv[7] = __uint_as_float(v.w & 0xFFFF0000u);
#pragma unroll
            for (int k = 0; k < 8; ++k) { ss[k] += xv[k]; qq[k] += xv[k] * xv[k]; }
        }
    }
    __shared__ float smS[F], smQ[F];
    for (int i = threadIdx.x; i < F; i += 256) { smS[i] = 0.f; smQ[i] = 0.f; }
    __syncthreads();
#pragma unroll
    for (int k = 0; k < 8; ++k) {
        atomicAdd(&smS[f0 + k], ss[k]);
        atomicAdd(&smQ[f0 + k], qq[k]);
    }
    __syncthreads();
    for (int i = threadIdx.x; i < F; i += 256) {
        sumP[(size_t)blockIdx.x * F + i] = smS[i];
        ssqP[(size_t)blockIdx.x * F + i] = smQ[i];
    }
}

// ---------------- BN params from partials: one block per feature ----------------

__global__ __launch_bounds__(256) void bnparam_kernel(const float* __restrict__ sumP,
                                                      const float* __restrict__ ssqP,
                                                      const float* __restrict__ gamma,
                                                      const float* __restrict__ beta,
                                                      float* __restrict__ S, float* __restrict__ T,
                                                      int n, int F, int NB) {
    const int f = blockIdx.x;
    const int t = threadIdx.x;
    float s = 0.f, q = 0.f;
    for (int b = t; b < NB; b += 256) {
        s += sumP[(size_t)b * F + f];
        q += ssqP[(size_t)b * F + f];
    }
    __shared__ float rs[4], rq[4];
    for (int o = 32; o; o >>= 1) { s += __shfl_down(s, o); q += __shfl_down(q, o); }
    if ((t & 63) == 0) { rs[t >> 6] = s; rq[t >> 6] = q; }
    __syncthreads();
    if (t == 0) {
        s = rs[0] + rs[1] + rs[2] + rs[3];
        q = rq[0] + rq[1] + rq[2] + rq[3];
        const float m = s / (float)n;
        const float var = q / (float)n - m * m;
        const float inv = rsqrtf(var + BN_EPS);
        const float sc = gamma[f] * inv;
        S[f] = sc;
        T[f] = beta[f] - m * sc;
    }
}

// ---------------- launch ----------------

extern "C" void kernel_launch(void* const* d_in, const int* in_sizes, int n_in,
                              void* d_out, int out_size, void* d_ws, size_t ws_size,
                              hipStream_t stream) {
    const float* x = (const float*)d_in[0];
    const int* edges = (const int*)d_in[1];   // [2, E] int32
    const float* W1 = (const float*)d_in[3];
    const float* b1 = (const float*)d_in[4];
    const float* W2 = (const float*)d_in[5];
    const float* b2 = (const float*)d_in[6];
    const float* W3 = (const float*)d_in[7];
    const float* b3 = (const float*)d_in[8];
    const float* gamma1 = (const float*)d_in[9];
    const float* beta1 = (const float*)d_in[10];
    const float* gamma2 = (const float*)d_in[11];
    const float* beta2 = (const float*)d_in[12];

    const int N = in_sizes[0] / 128;
    const int E = in_sizes[1] / 2;
    const int* esrc = edges;
    const int* edst = edges + E;
    const int nb = (N + BMASK) >> BSHIFT;       // dst buckets of 64 nodes
    const int M = nb * NBLK;                    // (bucket, chunk) fragments
    const int chunk = (E + NBLK - 1) / NBLK;
    const int NBS = 1024;                       // stats partial blocks

    char* ws = (char*)d_ws;
    size_t off = 0;
    auto alloc = [&](size_t bytes) -> void* {
        void* p = ws + off;
        off = (off + bytes + 255) & ~(size_t)255;
        return p;
    };
    int* hist = (int*)alloc((size_t)M * 4);
    int* S = (int*)alloc((size_t)M * 4);
    int* partials = (int*)alloc(1024 * 4);
    int* rowptr = (int*)alloc((size_t)(N + 1) * 4);
    float* dinv = (float*)alloc((size_t)N * 4);
    float* bn = (float*)alloc(512 * 4);
    float* sumP1 = (float*)alloc((size_t)NBS * 128 * 4);
    float* ssqP1 = (float*)alloc((size_t)NBS * 128 * 4);
    float* sumP2 = (float*)alloc((size_t)NBS * 64 * 4);
    float* ssqP2 = (float*)alloc((size_t)NBS * 64 * 4);
    unsigned short* wt1 = (unsigned short*)alloc(128 * 128 * 2);
    unsigned short* wt2 = (unsigned short*)alloc(64 * 128 * 2);
    int* csr = (int*)alloc((size_t)E * 4);
    unsigned short* hbuf = (unsigned short*)alloc((size_t)N * 128 * 2);  // bf16 h'
    unsigned short* ybuf = (unsigned short*)alloc((size_t)N * 128 * 2);  // bf16 y
    unsigned int* packed = (unsigned int*)hbuf;  // alias: dead before gemm1 writes hbuf

    float* sA = bn;
    float* tA = bn + 128;
    float* sB = bn + 256;
    float* tB = bn + 384;

    const int MB = (M + 1023) / 1024;   // scan blocks (<= 256)
    const int TBLK = (128 * 128 + 128 * 64 + 1023) / 1024;  // transpose tail blocks

    // preprocessing: chunked counting sort by dst (sub-binned by src>>13 within node lists)
    pre_kernel<<<NBLK + TBLK, 1024, 0, stream>>>(edst, hist, E, nb, chunk, W1, wt1, W2, wt2);
    scan_block_kernel<<<MB, 1024, 0, stream>>>(hist, S, partials, M);
    chunkscatter_kernel<<<NBLK, 1024, 0, stream>>>(esrc, edst, S, partials, packed, E, nb, chunk, MB);
    bucket_build_kernel<<<nb, 256, 0, stream>>>(packed, S, partials, rowptr, dinv, csr, N, nb, E, MB);

    // layer 1 (MFMA; agg split into 4 node-quarters — DIAGNOSTIC to expose sub-top-5 kernels)
    mgemm_kernel<128, false, false><<<(N + 63) / 64, 256, 0, stream>>>(x, wt1, nullptr, nullptr, dinv, hbuf, N);
    {
        const int q = (N + 3) / 4;
        for (int k = 0; k < 4; ++k) {
            const int a = k * q;
            const int bnd = min(N, a + q);
            if (a < bnd)
                agg_kernel<128, 16, true><<<(bnd - a + 15) / 16, 256, 0, stream>>>(hbuf, rowptr, csr, dinv, b1, ybuf, a, bnd);
        }
    }
    bstats_kernel<128><<<NBS, 256, 0, stream>>>(ybuf, sumP1, ssqP1, N, NBS);
    bnparam_kernel<<<128, 256, 0, stream>>>(sumP1, ssqP1, gamma1, beta1, sA, tA, N, 128, NBS);

    // layer 2 (MFMA, BN folded into bf16 stage; agg split into halves)
    mgemm_kernel<64, true, true><<<(N + 63) / 64, 256, 0, stream>>>(ybuf, wt2, sA, tA, dinv, hbuf, N);
    {
        const int hseg = (N + 1) / 2;
        for (int k = 0; k < 2; ++k) {
            const int a = k * hseg;
            const int bnd = min(N, a + hseg);
            if (a < bnd)
                agg_kernel<64, 8, true><<<(bnd - a + 31) / 32, 256, 0, stream>>>(hbuf, rowptr, csr, dinv, b2, ybuf, a, bnd);
        }
    }
    bstats_kernel<64><<<NBS, 256, 0, stream>>>(ybuf, sumP2, ssqP2, N, NBS);
    bnparam_kernel<<<64, 256, 0, stream>>>(sumP2, ssqP2, gamma2, beta2, sB, tB, N, 64, NBS);

    // layer 3 (small)
    gemm3_kernel<<<(N + 255) / 256, 256, 0, stream>>>(ybuf, W3, sB, tB, dinv, hbuf, N);
    agg_kernel<8, 1, false><<<(N + 255) / 256, 256, 0, stream>>>(hbuf, rowptr, csr, dinv, b3, (float*)d_out, 0, N);
}

// Round 13
// 260.989 us; speedup vs baseline: 1.0941x; 1.0941x over previous
//
#include <hip/hip_runtime.h>
#include <cstdint>
#include <cstddef>

#define NEG_SLOPE 0.01f
#define BN_EPS 1e-5f
#define BSHIFT 6
#define BMASK 63
#define NBLK 256   // scatter chunks (256 blocks -> full CU coverage)

using short8 = __attribute__((ext_vector_type(8))) short;
using f32x4 = __attribute__((ext_vector_type(4))) float;

__device__ inline unsigned short f2bf(float f) {   // RNE f32 -> bf16
    unsigned int u = __float_as_uint(f);
    u += 0x7FFFu + ((u >> 16) & 1u);
    return (unsigned short)(u >> 16);
}

// ---------------- pre: chunk histograms (blocks < NBLK) + W1/W2 transpose (rest) ----------------

__global__ __launch_bounds__(1024) void pre_kernel(const int* __restrict__ dst,
                                                   int* __restrict__ hist,
                                                   int E, int nb, int chunk,
                                                   const float* __restrict__ W1,
                                                   unsigned short* __restrict__ wt1,
                                                   const float* __restrict__ W2,
                                                   unsigned short* __restrict__ wt2) {
    const int b = blockIdx.x;
    if (b < NBLK) {
        __shared__ int lh[2048];
        for (int i = threadIdx.x; i < nb; i += 1024) lh[i] = 0;
        __syncthreads();
        const int e0 = b * chunk;
        const int e1 = min(E, e0 + chunk);
        for (int e = e0 + threadIdx.x; e < e1; e += 1024)
            atomicAdd(&lh[dst[e] >> BSHIFT], 1);
        __syncthreads();
        for (int k = threadIdx.x; k < nb; k += 1024)
            hist[k * NBLK + b] = lh[k];
    } else {
        int idx = (b - NBLK) * 1024 + threadIdx.x;
        if (idx < 128 * 128) {
            int k = idx >> 7, n = idx & 127;
            wt1[n * 128 + k] = f2bf(W1[idx]);
        } else if (idx < 128 * 128 + 128 * 64) {
            int j = idx - 128 * 128;
            int k = j >> 6, n = j & 63;
            wt2[n * 128 + k] = f2bf(W2[j]);
        }
    }
}

__global__ __launch_bounds__(1024) void scan_block_kernel(const int* __restrict__ in,
                                                          int* __restrict__ out,
                                                          int* __restrict__ partials, int n) {
    __shared__ int sm[1024];
    int tid = threadIdx.x;
    int i = blockIdx.x * 1024 + tid;
    int v = (i < n) ? in[i] : 0;
    int x = v;
    sm[tid] = x;
    __syncthreads();
    for (int off = 1; off < 1024; off <<= 1) {
        int y = (tid >= off) ? sm[tid - off] : 0;
        __syncthreads();
        x += y;
        sm[tid] = x;
        __syncthreads();
    }
    if (i < n) out[i] = x - v;           // exclusive
    if (tid == 1023) partials[blockIdx.x] = x;
}

// scatter: LDS cursors = scan + block-offset prefix (PARALLEL LDS scan of partials — r12 found
// the serial thread-0 prefix loop cost ~16 us/block of L2 latency)
__global__ __launch_bounds__(1024) void chunkscatter_kernel(const int* __restrict__ src,
                                                            const int* __restrict__ dst,
                                                            const int* __restrict__ S,
                                                            const int* __restrict__ partials,
                                                            unsigned int* __restrict__ packed,
                                                            int E, int nb, int chunk, int MB) {
    __shared__ int cur[2048];
    __shared__ int pof[1024];
    const int b = blockIdx.x;
    const int t = threadIdx.x;
    {   // exclusive scan of partials[0..MB) into pof (Hillis-Steele, 1024 threads)
        const int v = (t < MB) ? partials[t] : 0;
        int x = v;
        pof[t] = x;
        __syncthreads();
        for (int o = 1; o < 1024; o <<= 1) {
            int y = (t >= o) ? pof[t - o] : 0;
            __syncthreads();
            x += y;
            pof[t] = x;
            __syncthreads();
        }
        pof[t] = x - v;
        __syncthreads();
    }
    for (int k = t; k < nb; k += 1024) {
        const int i = k * NBLK + b;
        cur[k] = S[i] + pof[i >> 10];
    }
    __syncthreads();
    const int e0 = b * chunk;
    const int e1 = min(E, e0 + chunk);
    for (int e = e0 + t; e < e1; e += 1024) {
        int d = dst[e];
        int slot = atomicAdd(&cur[d >> BSHIFT], 1);
        packed[slot] = ((unsigned int)src[e] << BSHIFT) | (unsigned int)(d & BMASK);
    }
}

// per-bucket: counting sort by (ldst, src>>13) -> rowptr, dinv, src-binned csr lists.
__global__ __launch_bounds__(256) void bucket_build_kernel(const unsigned int* __restrict__ packed,
                                                           const int* __restrict__ S,
                                                           const int* __restrict__ partials,
                                                           int* __restrict__ rowptr,
                                                           float* __restrict__ dinv,
                                                           int* __restrict__ csr,
                                                           int N, int nb, int E, int MB) {
    const int b = blockIdx.x;
    const int t = threadIdx.x;
    __shared__ int pofS[1024];
    __shared__ int tsum[256];
    __shared__ int eb[2];
    {   // parallel exclusive scan of partials (4 entries/thread + block scan)
        const int b4 = t * 4;
        const int v0 = (b4     < MB) ? partials[b4]     : 0;
        const int v1 = (b4 + 1 < MB) ? partials[b4 + 1] : 0;
        const int v2 = (b4 + 2 < MB) ? partials[b4 + 2] : 0;
        const int v3 = (b4 + 3 < MB) ? partials[b4 + 3] : 0;
        const int s = v0 + v1 + v2 + v3;
        int x = s;
        tsum[t] = x;
        __syncthreads();
        for (int o = 1; o < 256; o <<= 1) {
            int y = (t >= o) ? tsum[t - o] : 0;
            __syncthreads();
            x += y;
            tsum[t] = x;
            __syncthreads();
        }
        const int excl = x - s;
        pofS[b4] = excl;
        pofS[b4 + 1] = excl + v0;
        pofS[b4 + 2] = excl + v0 + v1;
        pofS[b4 + 3] = excl + v0 + v1 + v2;
        __syncthreads();
    }
    if (t == 0) {
        const int i0 = b * NBLK;
        eb[0] = S[i0] + pofS[i0 >> 10];
        if (b == nb - 1) eb[1] = E;
        else {
            const int i1 = (b + 1) * NBLK;
            eb[1] = S[i1] + pofS[i1 >> 10];
        }
    }
    __syncthreads();
    const int e0 = eb[0], e1 = eb[1];
    const int node0 = b << BSHIFT;
    __shared__ int h2[1024];    // [ldst][16] sub-bin hist -> exclusive scan -> cursors
    for (int i = t; i < 1024; i += 256) h2[i] = 0;
    __syncthreads();
    for (int e = e0 + t; e < e1; e += 256) {
        const unsigned int p = packed[e];
        const int ldst = p & BMASK;
        int s4 = (int)(p >> BSHIFT) >> 13;      // 0..12 for N=100000
        if (s4 > 15) s4 = 15;
        atomicAdd(&h2[(ldst << 4) | s4], 1);
    }
    __syncthreads();
    // exclusive scan of 1024 entries (4 per thread)
    const int v0 = h2[4 * t], v1 = h2[4 * t + 1], v2 = h2[4 * t + 2], v3 = h2[4 * t + 3];
    const int tot = v0 + v1 + v2 + v3;
    int x = tot;
    tsum[t] = x;
    __syncthreads();
    for (int o = 1; o < 256; o <<= 1) {
        int y = (t >= o) ? tsum[t - o] : 0;
        __syncthreads();
        x += y;
        tsum[t] = x;
        __syncthreads();
    }
    const int base = e0 + x - tot;
    h2[4 * t] = base;
    h2[4 * t + 1] = base + v0;
    h2[4 * t + 2] = base + v0 + v1;
    h2[4 * t + 3] = base + v0 + v1 + v2;
    __syncthreads();
    if (t < 64) {
        const int gs = h2[t << 4];
        const int ge = (t == 63) ? e1 : h2[(t + 1) << 4];
        const int node = node0 + t;
        if (node < N) {
            rowptr[node] = gs;
            dinv[node] = rsqrtf((float)(ge - gs + 1));   // +1 self-loop
        }
    }
    if (b == nb - 1 && t == 0) rowptr[N] = E;
    __syncthreads();
    for (int e = e0 + t; e < e1; e += 256) {
        const unsigned int p = packed[e];
        const int ldst = p & BMASK;
        const int src = (int)(p >> BSHIFT);
        int s4 = src >> 13;
        if (s4 > 15) s4 = 15;
        const int slot = atomicAdd(&h2[(ldst << 4) | s4], 1);
        csr[slot] = src;
    }
}

// ---------------- MFMA GEMM: H'[row] = bf16( dinv[row] * (bn(X)[row] @ W) ) ----------------

template <int MF, bool BN, bool XBF>
__global__ __launch_bounds__(256) void mgemm_kernel(const void* __restrict__ Xv,
                                                    const unsigned short* __restrict__ Wt,
                                                    const float* __restrict__ bnS,
                                                    const float* __restrict__ bnT,
                                                    const float* __restrict__ dinv,
                                                    unsigned short* __restrict__ H, int n) {
    constexpr int K = 128;
    constexpr int CTW = (MF / 16) / 4;           // col-tiles per wave (2 or 1)
    __shared__ unsigned short Xl[64 * K];        // 16 KB, reused as output tile
    __shared__ unsigned short Wl[MF * K];        // 32/16 KB
    __shared__ float dl[64];

    const int t = threadIdx.x;
    const int wave = t >> 6;
    const int lane = t & 63;
    const int row0 = blockIdx.x * 64;

    if (XBF) {
        const unsigned short* X = (const unsigned short*)Xv;
        for (int idx = t; idx < 64 * K / 8; idx += 256) {
            int r = idx >> 4, c8 = idx & 15;
            int row = row0 + r; if (row >= n) row = n - 1;
            uint4 v = ((const uint4*)(X + (size_t)row * K))[c8];
            float xv[8];
            xv[0] = __uint_as_float(v.x << 16); xv[1] = __uint_as_float(v.x & 0xFFFF0000u);
            xv[2] = __uint_as_float(v.y << 16); xv[3] = __uint_as_float(v.y & 0xFFFF0000u);
            xv[4] = __uint_as_float(v.z << 16); xv[5] = __uint_as_float(v.z & 0xFFFF0000u);
            xv[6] = __uint_as_float(v.w << 16); xv[7] = __uint_as_float(v.w & 0xFFFF0000u);
            if (BN) {
                const float4 s0 = ((const float4*)bnS)[c8 * 2];
                const float4 s1 = ((const float4*)bnS)[c8 * 2 + 1];
                const float4 t0 = ((const float4*)bnT)[c8 * 2];
                const float4 t1 = ((const float4*)bnT)[c8 * 2 + 1];
                xv[0] = xv[0] * s0.x + t0.x; xv[1] = xv[1] * s0.y + t0.y;
                xv[2] = xv[2] * s0.z + t0.z; xv[3] = xv[3] * s0.w + t0.w;
                xv[4] = xv[4] * s1.x + t1.x; xv[5] = xv[5] * s1.y + t1.y;
                xv[6] = xv[6] * s1.z + t1.z; xv[7] = xv[7] * s1.w + t1.w;
            }
            uint4 o;
            o.x = (unsigned)f2bf(xv[0]) | ((unsigned)f2bf(xv[1]) << 16);
            o.y = (unsigned)f2bf(xv[2]) | ((unsigned)f2bf(xv[3]) << 16);
            o.z = (unsigned)f2bf(xv[4]) | ((unsigned)f2bf(xv[5]) << 16);
            o.w = (unsigned)f2bf(xv[6]) | ((unsigned)f2bf(xv[7]) << 16);
            *(uint4*)((char*)Xl + r * 256 + ((c8 * 16) ^ ((r & 7) << 4))) = o;
        }
    } else {
        const float* X = (const float*)Xv;
        for (int idx = t; idx < 64 * K / 4; idx += 256) {
            int r = idx >> 5, c4 = idx & 31;
            int row = row0 + r; if (row >= n) row = n - 1;
            float4 v = ((const float4*)(X + (size_t)row * K))[c4];
            if (BN) {
                float4 sv = ((const float4*)bnS)[c4];
                float4 tv = ((const float4*)bnT)[c4];
                v.x = v.x * sv.x + tv.x; v.y = v.y * sv.y + tv.y;
                v.z = v.z * sv.z + tv.z; v.w = v.w * sv.w + tv.w;
            }
            ushort4 o; o.x = f2bf(v.x); o.y = f2bf(v.y); o.z = f2bf(v.z); o.w = f2bf(v.w);
            *(ushort4*)((char*)Xl + r * 256 + ((c4 * 8) ^ ((r & 7) << 4))) = o;
        }
    }
    for (int idx = t; idx < MF * K / 4; idx += 256) {
        int nr = idx >> 5, k4 = idx & 31;
        ushort4 o = ((const ushort4*)(Wt + (size_t)nr * K))[k4];
        *(ushort4*)((char*)Wl + nr * 256 + ((k4 * 8) ^ ((nr & 7) << 4))) = o;
    }
    if (t < 64) { int row = row0 + t; dl[t] = dinv[row < n ? row : n - 1]; }
    __syncthreads();

    f32x4 acc[CTW][4];
#pragma unroll
    for (int c = 0; c < CTW; ++c)
#pragma unroll
        for (int rt = 0; rt < 4; ++rt)
            acc[c][rt] = (f32x4){0.f, 0.f, 0.f, 0.f};

    const int kg = lane >> 4;       // k-group 0..3
    const int lr = lane & 15;       // row (A) / col (B)

#pragma unroll
    for (int kk = 0; kk < 4; ++kk) {
        const int kb = (kk * 32 + kg * 8) * 2;   // byte offset of the 8 bf16 k-slice
        short8 a[4];
#pragma unroll
        for (int rt = 0; rt < 4; ++rt) {
            int r = rt * 16 + lr;
            a[rt] = *(const short8*)((const char*)Xl + r * 256 + (kb ^ ((r & 7) << 4)));
        }
#pragma unroll
        for (int c = 0; c < CTW; ++c) {
            int nr = (wave * CTW + c) * 16 + lr;
            short8 b = *(const short8*)((const char*)Wl + nr * 256 + (kb ^ ((nr & 7) << 4)));
#pragma unroll
            for (int rt = 0; rt < 4; ++rt)
                acc[c][rt] = __builtin_amdgcn_mfma_f32_16x16x32_bf16(a[rt], b, acc[c][rt], 0, 0, 0);
        }
    }
    __syncthreads();   // done reading Xl; reuse as output tile [64][MF]

    unsigned short* Ol = (unsigned short*)Xl;
#pragma unroll
    for (int c = 0; c < CTW; ++c) {
        int col = (wave * CTW + c) * 16 + lr;
#pragma unroll
        for (int rt = 0; rt < 4; ++rt) {
#pragma unroll
            for (int j = 0; j < 4; ++j) {
                int r = rt * 16 + kg * 4 + j;
                Ol[r * MF + col] = f2bf(acc[c][rt][j] * dl[r]);
            }
        }
    }
    __syncthreads();
    for (int idx = t; idx < 64 * MF / 4; idx += 256) {
        int r = idx / (MF / 4), c4 = idx % (MF / 4);
        int row = row0 + r;
        if (row < n)
            ((ushort4*)(H + (size_t)row * MF))[c4] = ((const ushort4*)Ol)[idx];
    }
}

// ---------------- layer-3 GEMM: bf16 X [n][64] -> bf16 h3' [n][8] ----------------

__global__ __launch_bounds__(256) void gemm3_kernel(const unsigned short* __restrict__ X,
                                                    const float* __restrict__ W,   // [64][8]
                                                    const float* __restrict__ bnS,
                                                    const float* __restrict__ bnT,
                                                    const float* __restrict__ dinv,
                                                    unsigned short* __restrict__ H, int n) {
    __shared__ float Wl[512];
    __shared__ float sl[64], tl[64];
    const int t = threadIdx.x;
    for (int i = t; i < 512; i += 256) Wl[i] = W[i];
    if (t < 64) { sl[t] = bnS[t]; tl[t] = bnT[t]; }
    __syncthreads();
    const int node = blockIdx.x * 256 + t;
    if (node >= n) return;
    float acc[8];
#pragma unroll
    for (int m = 0; m < 8; ++m) acc[m] = 0.f;
    const uint4* xp = (const uint4*)(X + (size_t)node * 64);
#pragma unroll
    for (int c8 = 0; c8 < 8; ++c8) {
        const uint4 v = xp[c8];
        float xv[8];
        xv[0] = __uint_as_float(v.x << 16); xv[1] = __uint_as_float(v.x & 0xFFFF0000u);
        xv[2] = __uint_as_float(v.y << 16); xv[3] = __uint_as_float(v.y & 0xFFFF0000u);
        xv[4] = __uint_as_float(v.z << 16); xv[5] = __uint_as_float(v.z & 0xFFFF0000u);
        xv[6] = __uint_as_float(v.w << 16); xv[7] = __uint_as_float(v.w & 0xFFFF0000u);
#pragma unroll
        for (int j = 0; j < 8; ++j) {
            const int k = c8 * 8 + j;
            const float x = xv[j] * sl[k] + tl[k];
#pragma unroll
            for (int m = 0; m < 8; ++m) acc[m] += x * Wl[k * 8 + m];
        }
    }
    const float di = dinv[node];
    uint4 o;
    o.x = (unsigned)f2bf(acc[0] * di) | ((unsigned)f2bf(acc[1] * di) << 16);
    o.y = (unsigned)f2bf(acc[2] * di) | ((unsigned)f2bf(acc[3] * di) << 16);
    o.z = (unsigned)f2bf(acc[4] * di) | ((unsigned)f2bf(acc[5] * di) << 16);
    o.w = (unsigned)f2bf(acc[6] * di) | ((unsigned)f2bf(acc[7] * di) << 16);
    *(uint4*)(H + (size_t)node * 8) = o;
}

// ---------------- aggregation: y = leaky( di*(sum_row h'[s] + h'[self]) + b ) ----------------
// Exact grid, x4 unroll, VGPR 28 — measured-optimal concurrency shape (r7/r9: 60.8 us).

template <int F, int GROUP, bool BF16OUT>
__global__ __launch_bounds__(256) void agg_kernel(const unsigned short* __restrict__ h,
                                                  const int* __restrict__ rowptr,
                                                  const int* __restrict__ csr,
                                                  const float* __restrict__ dinv,
                                                  const float* __restrict__ bias,
                                                  void* __restrict__ yout, int n) {
    constexpr int NPB = 256 / GROUP;
    const int g = threadIdx.x % GROUP;
    const int node = blockIdx.x * NPB + threadIdx.x / GROUP;
    if (node >= n) return;
    const int f0 = g * 8;
    const unsigned short* hp = h + f0;
    float a0 = 0.f, a1 = 0.f, a2 = 0.f, a3 = 0.f, a4 = 0.f, a5 = 0.f, a6 = 0.f, a7 = 0.f;
#define ACC8(v)                                    \
    a0 += __uint_as_float((v).x << 16);            \
    a1 += __uint_as_float((v).x & 0xFFFF0000u);    \
    a2 += __uint_as_float((v).y << 16);            \
    a3 += __uint_as_float((v).y & 0xFFFF0000u);    \
    a4 += __uint_as_float((v).z << 16);            \
    a5 += __uint_as_float((v).z & 0xFFFF0000u);    \
    a6 += __uint_as_float((v).w << 16);            \
    a7 += __uint_as_float((v).w & 0xFFFF0000u);
    int e = rowptr[node];
    const int r1 = rowptr[node + 1];
    for (; e + 4 <= r1; e += 4) {
        const int s0 = csr[e], s1 = csr[e + 1], s2 = csr[e + 2], s3 = csr[e + 3];
        const uint4 v0 = *(const uint4*)(hp + (size_t)s0 * F);
        const uint4 v1 = *(const uint4*)(hp + (size_t)s1 * F);
        const uint4 v2 = *(const uint4*)(hp + (size_t)s2 * F);
        const uint4 v3 = *(const uint4*)(hp + (size_t)s3 * F);
        ACC8(v0); ACC8(v1); ACC8(v2); ACC8(v3);
    }
    for (; e < r1; ++e) {
        const int s = csr[e];
        const uint4 v = *(const uint4*)(hp + (size_t)s * F);
        ACC8(v);
    }
    {   // self term (h' already contains dinv[self] factor)
        const uint4 v = *(const uint4*)(hp + (size_t)node * F);
        ACC8(v);
    }
#undef ACC8
    const float di = dinv[node];
    const float4 bA = *(const float4*)(bias + f0);
    const float4 bB = *(const float4*)(bias + f0 + 4);
    float r[8];
    r[0] = di * a0 + bA.x; r[1] = di * a1 + bA.y;
    r[2] = di * a2 + bA.z; r[3] = di * a3 + bA.w;
    r[4] = di * a4 + bB.x; r[5] = di * a5 + bB.y;
    r[6] = di * a6 + bB.z; r[7] = di * a7 + bB.w;
#pragma unroll
    for (int k = 0; k < 8; ++k) r[k] = r[k] > 0.f ? r[k] : NEG_SLOPE * r[k];
    if (BF16OUT) {
        uint4 o;
        o.x = (unsigned)f2bf(r[0]) | ((unsigned)f2bf(r[1]) << 16);
        o.y = (unsigned)f2bf(r[2]) | ((unsigned)f2bf(r[3]) << 16);
        o.z = (unsigned)f2bf(r[4]) | ((unsigned)f2bf(r[5]) << 16);
        o.w = (unsigned)f2bf(r[6]) | ((unsigned)f2bf(r[7]) << 16);
        *(uint4*)((unsigned short*)yout + (size_t)node * F + f0) = o;
    } else {
        float4 o0, o1;
        o0.x = r[0]; o0.y = r[1]; o0.z = r[2]; o0.w = r[3];
        o1.x = r[4]; o1.y = r[5]; o1.z = r[6]; o1.w = r[7];
        float* yp = (float*)yout + (size_t)node * F + f0;
        *(float4*)(yp) = o0;
        *(float4*)(yp + 4) = o1;
    }
}

// ---------------- BN statistics over bf16 y: per-block partials ----------------

template <int F>
__global__ __launch_bounds__(256) void bstats_kernel(const unsigned short* __restrict__ y,
                                                     float* __restrict__ sumP,
                                                     float* __restrict__ ssqP,
                                                     int n, int nblocks) {
    constexpr int GROUP = F / 8;
    constexpr int NPB = 256 / GROUP;
    const int g = threadIdx.x % GROUP;
    const int slot = threadIdx.x / GROUP;
    const int f0 = g * 8;
    float ss[8], qq[8];
#pragma unroll
    for (int k = 0; k < 8; ++k) { ss[k] = 0.f; qq[k] = 0.f; }
    for (int base = blockIdx.x * NPB; base < n; base += nblocks * NPB) {
        const int node = base + slot;
        if (node < n) {
            const uint4 v = *(const uint4*)(y + (size_t)node * F + f0);
            float xv[8];
            xv[0] = __uint_as_float(v.x << 16); xv[1] = __uint_as_float(v.x & 0xFFFF0000u);
            xv[2] = __uint_as_float(v.y << 16); xv[3] = __uint_as_float(v.y & 0xFFFF0000u);
            xv[4] = __uint_as_float(v.z << 16); xv[5] = __uint_as_float(v.z & 0xFFFF0000u);
            xv[6] = __uint_as_float(v.w << 16); xv[7] = __uint_as_float(v.w & 0xFFFF0000u);
#pragma unroll
            for (int k = 0; k < 8; ++k) { ss[k] += xv[k]; qq[k] += xv[k] * xv[k]; }
        }
    }
    __shared__ float smS[F], smQ[F];
    for (int i = threadIdx.x; i < F; i += 256) { smS[i] = 0.f; smQ[i] = 0.f; }
    __syncthreads();
#pragma unroll
    for (int k = 0; k < 8; ++k) {
        atomicAdd(&smS[f0 + k], ss[k]);
        atomicAdd(&smQ[f0 + k], qq[k]);
    }
    __syncthreads();
    for (int i = threadIdx.x; i < F; i += 256) {
        sumP[(size_t)blockIdx.x * F + i] = smS[i];
        ssqP[(size_t)blockIdx.x * F + i] = smQ[i];
    }
}

// ---------------- BN params from partials: one block per feature ----------------

__global__ __launch_bounds__(256) void bnparam_kernel(const float* __restrict__ sumP,
                                                      const float* __restrict__ ssqP,
                                                      const float* __restrict__ gamma,
                                                      const float* __restrict__ beta,
                                                      float* __restrict__ S, float* __restrict__ T,
                                                      int n, int F, int NB) {
    const int f = blockIdx.x;
    const int t = threadIdx.x;
    float s = 0.f, q = 0.f;
    for (int b = t; b < NB; b += 256) {
        s += sumP[(size_t)b * F + f];
        q += ssqP[(size_t)b * F + f];
    }
    __shared__ float rs[4], rq[4];
    for (int o = 32; o; o >>= 1) { s += __shfl_down(s, o); q += __shfl_down(q, o); }
    if ((t & 63) == 0) { rs[t >> 6] = s; rq[t >> 6] = q; }
    __syncthreads();
    if (t == 0) {
        s = rs[0] + rs[1] + rs[2] + rs[3];
        q = rq[0] + rq[1] + rq[2] + rq[3];
        const float m = s / (float)n;
        const float var = q / (float)n - m * m;
        const float inv = rsqrtf(var + BN_EPS);
        const float sc = gamma[f] * inv;
        S[f] = sc;
        T[f] = beta[f] - m * sc;
    }
}

// ---------------- launch ----------------

extern "C" void kernel_launch(void* const* d_in, const int* in_sizes, int n_in,
                              void* d_out, int out_size, void* d_ws, size_t ws_size,
                              hipStream_t stream) {
    const float* x = (const float*)d_in[0];
    const int* edges = (const int*)d_in[1];   // [2, E] int32
    const float* W1 = (const float*)d_in[3];
    const float* b1 = (const float*)d_in[4];
    const float* W2 = (const float*)d_in[5];
    const float* b2 = (const float*)d_in[6];
    const float* W3 = (const float*)d_in[7];
    const float* b3 = (const float*)d_in[8];
    const float* gamma1 = (const float*)d_in[9];
    const float* beta1 = (const float*)d_in[10];
    const float* gamma2 = (const float*)d_in[11];
    const float* beta2 = (const float*)d_in[12];

    const int N = in_sizes[0] / 128;
    const int E = in_sizes[1] / 2;
    const int* esrc = edges;
    const int* edst = edges + E;
    const int nb = (N + BMASK) >> BSHIFT;       // dst buckets of 64 nodes
    const int M = nb * NBLK;                    // (bucket, chunk) fragments
    const int chunk = (E + NBLK - 1) / NBLK;
    const int NBS = 1024;                       // stats partial blocks

    char* ws = (char*)d_ws;
    size_t off = 0;
    auto alloc = [&](size_t bytes) -> void* {
        void* p = ws + off;
        off = (off + bytes + 255) & ~(size_t)255;
        return p;
    };
    int* hist = (int*)alloc((size_t)M * 4);
    int* S = (int*)alloc((size_t)M * 4);
    int* partials = (int*)alloc(1024 * 4);
    int* rowptr = (int*)alloc((size_t)(N + 1) * 4);
    float* dinv = (float*)alloc((size_t)N * 4);
    float* bn = (float*)alloc(512 * 4);
    float* sumP1 = (float*)alloc((size_t)NBS * 128 * 4);
    float* ssqP1 = (float*)alloc((size_t)NBS * 128 * 4);
    float* sumP2 = (float*)alloc((size_t)NBS * 64 * 4);
    float* ssqP2 = (float*)alloc((size_t)NBS * 64 * 4);
    unsigned short* wt1 = (unsigned short*)alloc(128 * 128 * 2);
    unsigned short* wt2 = (unsigned short*)alloc(64 * 128 * 2);
    int* csr = (int*)alloc((size_t)E * 4);
    unsigned short* hbuf = (unsigned short*)alloc((size_t)N * 128 * 2);  // bf16 h'
    unsigned short* ybuf = (unsigned short*)alloc((size_t)N * 128 * 2);  // bf16 y
    unsigned int* packed = (unsigned int*)hbuf;  // alias: dead before gemm1 writes hbuf

    float* sA = bn;
    float* tA = bn + 128;
    float* sB = bn + 256;
    float* tB = bn + 384;

    const int MB = (M + 1023) / 1024;   // scan blocks (<= 1024; 391 at N=100K)
    const int TBLK = (128 * 128 + 128 * 64 + 1023) / 1024;  // transpose tail blocks

    // preprocessing: chunked counting sort by dst (sub-binned by src>>13 within node lists)
    pre_kernel<<<NBLK + TBLK, 1024, 0, stream>>>(edst, hist, E, nb, chunk, W1, wt1, W2, wt2);
    scan_block_kernel<<<MB, 1024, 0, stream>>>(hist, S, partials, M);
    chunkscatter_kernel<<<NBLK, 1024, 0, stream>>>(esrc, edst, S, partials, packed, E, nb, chunk, MB);
    bucket_build_kernel<<<nb, 256, 0, stream>>>(packed, S, partials, rowptr, dinv, csr, N, nb, E, MB);

    // layer 1 (MFMA; agg exact-grid x4-unroll; stats streamed from bf16 y)
    mgemm_kernel<128, false, false><<<(N + 63) / 64, 256, 0, stream>>>(x, wt1, nullptr, nullptr, dinv, hbuf, N);
    agg_kernel<128, 16, true><<<(N + 15) / 16, 256, 0, stream>>>(hbuf, rowptr, csr, dinv, b1, ybuf, N);
    bstats_kernel<128><<<NBS, 256, 0, stream>>>(ybuf, sumP1, ssqP1, N, NBS);
    bnparam_kernel<<<128, 256, 0, stream>>>(sumP1, ssqP1, gamma1, beta1, sA, tA, N, 128, NBS);

    // layer 2 (MFMA, BN folded into bf16 stage)
    mgemm_kernel<64, true, true><<<(N + 63) / 64, 256, 0, stream>>>(ybuf, wt2, sA, tA, dinv, hbuf, N);
    agg_kernel<64, 8, true><<<(N + 31) / 32, 256, 0, stream>>>(hbuf, rowptr, csr, dinv, b2, ybuf, N);
    bstats_kernel<64><<<NBS, 256, 0, stream>>>(ybuf, sumP2, ssqP2, N, NBS);
    bnparam_kernel<<<64, 256, 0, stream>>>(sumP2, ssqP2, gamma2, beta2, sB, tB, N, 64, NBS);

    // layer 3 (small)
    gemm3_kernel<<<(N + 255) / 256, 256, 0, stream>>>(ybuf, W3, sB, tB, dinv, hbuf, N);
    agg_kernel<8, 1, false><<<(N + 255) / 256, 256, 0, stream>>>(hbuf, rowptr, csr, dinv, b3, (float*)d_out, N);
}